// Round 1
// baseline (99.304 us; speedup 1.0000x reference)
//
#include <hip/hip_runtime.h>
#include <hip/hip_bf16.h>

#define NN 512
#define DD 512
#define MARGIN_F 1.0f

// ---------------- kernel 0: row norms + zero dist + zero accumulators ----
__global__ __launch_bounds__(64) void k_init(const float* __restrict__ E,
                                             float* __restrict__ sq,
                                             float* __restrict__ dist,
                                             double* __restrict__ g_sum,
                                             unsigned long long* __restrict__ g_cnt) {
    const int r = blockIdx.x;
    const int lane = threadIdx.x;  // 64
    const float4* row = reinterpret_cast<const float4*>(E + (size_t)r * DD);
    float4 v0 = row[lane];
    float4 v1 = row[lane + 64];
    float s = v0.x * v0.x + v0.y * v0.y + v0.z * v0.z + v0.w * v0.w +
              v1.x * v1.x + v1.y * v1.y + v1.z * v1.z + v1.w * v1.w;
#pragma unroll
    for (int off = 32; off > 0; off >>= 1) s += __shfl_down(s, off);
    if (lane == 0) sq[r] = s;
    // zero dist row r (needed for split-K atomic accumulation)
    float4* drow = reinterpret_cast<float4*>(dist + (size_t)r * NN);
    float4 z = make_float4(0.f, 0.f, 0.f, 0.f);
    drow[lane] = z;
    drow[lane + 64] = z;
    if (r == 0 && lane == 0) {
        *g_sum = 0.0;
        *g_cnt = 0ull;
    }
}

// ---------------- kernel 1: dist = sq_i + sq_j - 2 * E E^T ---------------
// BM=BN=64, BK=32, 256 threads (16x16, 4x4 micro-tile), split-K=4.
constexpr int BM = 64, BN = 64, BK = 32, KSPLIT = 4, KCH = DD / KSPLIT;

__global__ __launch_bounds__(256) void k_gram_dist(const float* __restrict__ E,
                                                   const float* __restrict__ sq,
                                                   float* __restrict__ dist) {
    __shared__ float As[BK][BM + 4];  // k-major, +4 pad
    __shared__ float Bs[BK][BN + 4];
    const int tid = threadIdx.x;
    const int tx = tid & 15, ty = tid >> 4;
    const int row0 = blockIdx.y * BM, col0 = blockIdx.x * BN;
    const int k0 = blockIdx.z * KCH;
    float acc[4][4] = {};
    for (int kt = 0; kt < KCH; kt += BK) {
#pragma unroll
        for (int q = 0; q < 2; ++q) {
            int idx = tid + q * 256;  // 0..511
            int r = idx >> 3;         // 0..63
            int kv = idx & 7;         // float4 within the 32-wide K tile
            float4 va = *reinterpret_cast<const float4*>(
                &E[(size_t)(row0 + r) * DD + k0 + kt + kv * 4]);
            As[kv * 4 + 0][r] = va.x;
            As[kv * 4 + 1][r] = va.y;
            As[kv * 4 + 2][r] = va.z;
            As[kv * 4 + 3][r] = va.w;
            float4 vb = *reinterpret_cast<const float4*>(
                &E[(size_t)(col0 + r) * DD + k0 + kt + kv * 4]);
            Bs[kv * 4 + 0][r] = vb.x;
            Bs[kv * 4 + 1][r] = vb.y;
            Bs[kv * 4 + 2][r] = vb.z;
            Bs[kv * 4 + 3][r] = vb.w;
        }
        __syncthreads();
#pragma unroll
        for (int k = 0; k < BK; ++k) {
            float4 av = *reinterpret_cast<const float4*>(&As[k][ty * 4]);
            float4 bv = *reinterpret_cast<const float4*>(&Bs[k][tx * 4]);
            float a[4] = {av.x, av.y, av.z, av.w};
            float b[4] = {bv.x, bv.y, bv.z, bv.w};
#pragma unroll
            for (int i = 0; i < 4; ++i)
#pragma unroll
                for (int j = 0; j < 4; ++j) acc[i][j] += a[i] * b[j];
        }
        __syncthreads();
    }
    const bool addSq = (blockIdx.z == 0);
#pragma unroll
    for (int i = 0; i < 4; ++i) {
        int gi = row0 + ty * 4 + i;
        float sqi = addSq ? sq[gi] : 0.f;
#pragma unroll
        for (int j = 0; j < 4; ++j) {
            int gj = col0 + tx * 4 + j;
            float add = -2.0f * acc[i][j];
            if (addSq) add += sqi + sq[gj];
            atomicAdd(&dist[(size_t)gi * NN + gj], add);
        }
    }
}

// ---------------- kernel 2: per-anchor triplet accumulation --------------
__global__ __launch_bounds__(256) void k_triplet(const float* __restrict__ dist,
                                                 const int* __restrict__ labels,
                                                 double* __restrict__ g_sum,
                                                 unsigned long long* __restrict__ g_cnt) {
    const int a = blockIdx.x;
    const int tid = threadIdx.x;
    __shared__ float posv[NN];
    __shared__ int nPos;
    if (tid == 0) nPos = 0;
    __syncthreads();
    const int la = labels[a];
    float dval[2];
    int neg[2];
#pragma unroll
    for (int q = 0; q < 2; ++q) {
        int j = tid + q * 256;
        float d = dist[(size_t)a * NN + j];
        int lj = labels[j];
        dval[q] = d;
        neg[q] = 0;
        if (j != a) {
            if (lj == la) {
                int p = atomicAdd(&nPos, 1);
                posv[p] = d;
            } else {
                neg[q] = 1;
            }
        }
    }
    __syncthreads();
    const int np = nPos;  // block-uniform
    float acc = 0.f;
#pragma unroll
    for (int q = 0; q < 2; ++q) {
        if (neg[q]) {
            float d = dval[q];
            for (int p = 0; p < np; ++p) {
                float t = posv[p] - d + MARGIN_F;
                acc += fmaxf(t, 0.f);
            }
        }
    }
#pragma unroll
    for (int off = 32; off > 0; off >>= 1) acc += __shfl_down(acc, off);
    __shared__ float wsum[4];
    if ((tid & 63) == 0) wsum[tid >> 6] = acc;
    __syncthreads();
    if (tid == 0) {
        double tot = (double)wsum[0] + (double)wsum[1] + (double)wsum[2] + (double)wsum[3];
        atomicAdd(g_sum, tot);
        atomicAdd(g_cnt, (unsigned long long)((long long)np * (511 - np)));
    }
}

// ---------------- kernel 3: finalize -------------------------------------
__global__ void k_finalize(const double* __restrict__ g_sum,
                           const unsigned long long* __restrict__ g_cnt,
                           float* __restrict__ out) {
    if (threadIdx.x == 0) {
        unsigned long long c = *g_cnt;
        if (c < 1ull) c = 1ull;
        out[0] = (float)(*g_sum / (double)c);
    }
}

extern "C" void kernel_launch(void* const* d_in, const int* in_sizes, int n_in,
                              void* d_out, int out_size, void* d_ws, size_t ws_size,
                              hipStream_t stream) {
    const float* E = (const float*)d_in[0];
    const int* labels = (const int*)d_in[1];
    float* out = (float*)d_out;

    // workspace layout
    float* dist = (float*)d_ws;                                    // 512*512*4 = 1 MiB
    float* sq = (float*)((char*)d_ws + (size_t)NN * NN * 4);       // 2 KiB
    double* g_sum = (double*)((char*)d_ws + (size_t)NN * NN * 4 + 4096);
    unsigned long long* g_cnt = (unsigned long long*)(g_sum + 1);

    k_init<<<NN, 64, 0, stream>>>(E, sq, dist, g_sum, g_cnt);
    k_gram_dist<<<dim3(NN / BN, NN / BM, KSPLIT), 256, 0, stream>>>(E, sq, dist);
    k_triplet<<<NN, 256, 0, stream>>>(dist, labels, g_sum, g_cnt);
    k_finalize<<<1, 1, 0, stream>>>(g_sum, g_cnt, out);
}

// Round 2
// 69.495 us; speedup vs baseline: 1.4289x; 1.4289x over previous
//
#include <hip/hip_runtime.h>
#include <hip/hip_bf16.h>

#define NN 512
#define DD 512
#define MARGIN_F 1.0f

constexpr int BM = 64, BN = 64, BK = 32, KSPLIT = 4, KCH = DD / KSPLIT;

// ---------------- kernel 1: partial grams part[z] = E_z E_z^T ------------
// Plain stores (no init needed, no atomics). Diagonal blocks also write
// diag[z][j] = part[z][j][j].
__global__ __launch_bounds__(256) void k_gram(const float* __restrict__ E,
                                              float* __restrict__ part,
                                              float* __restrict__ diag) {
    __shared__ float As[BK][BM + 4];  // k-major, +4 pad
    __shared__ float Bs[BK][BN + 4];
    const int tid = threadIdx.x;
    const int tx = tid & 15, ty = tid >> 4;
    const int row0 = blockIdx.y * BM, col0 = blockIdx.x * BN;
    const int z = blockIdx.z;
    const int k0 = z * KCH;
    float acc[4][4] = {};
    for (int kt = 0; kt < KCH; kt += BK) {
#pragma unroll
        for (int q = 0; q < 2; ++q) {
            int idx = tid + q * 256;  // 0..511
            int r = idx >> 3;         // 0..63
            int kv = idx & 7;         // float4 within the 32-wide K tile
            float4 va = *reinterpret_cast<const float4*>(
                &E[(size_t)(row0 + r) * DD + k0 + kt + kv * 4]);
            As[kv * 4 + 0][r] = va.x;
            As[kv * 4 + 1][r] = va.y;
            As[kv * 4 + 2][r] = va.z;
            As[kv * 4 + 3][r] = va.w;
            float4 vb = *reinterpret_cast<const float4*>(
                &E[(size_t)(col0 + r) * DD + k0 + kt + kv * 4]);
            Bs[kv * 4 + 0][r] = vb.x;
            Bs[kv * 4 + 1][r] = vb.y;
            Bs[kv * 4 + 2][r] = vb.z;
            Bs[kv * 4 + 3][r] = vb.w;
        }
        __syncthreads();
#pragma unroll
        for (int k = 0; k < BK; ++k) {
            float4 av = *reinterpret_cast<const float4*>(&As[k][ty * 4]);
            float4 bv = *reinterpret_cast<const float4*>(&Bs[k][tx * 4]);
            float a[4] = {av.x, av.y, av.z, av.w};
            float b[4] = {bv.x, bv.y, bv.z, bv.w};
#pragma unroll
            for (int i = 0; i < 4; ++i)
#pragma unroll
                for (int j = 0; j < 4; ++j) acc[i][j] += a[i] * b[j];
        }
        __syncthreads();
    }
    float* pz = part + (size_t)z * NN * NN;
#pragma unroll
    for (int i = 0; i < 4; ++i) {
        int gi = row0 + ty * 4 + i;
        float4 st = make_float4(acc[i][0], acc[i][1], acc[i][2], acc[i][3]);
        *reinterpret_cast<float4*>(&pz[(size_t)gi * NN + col0 + tx * 4]) = st;
    }
    if (row0 == col0 && tx == ty) {
#pragma unroll
        for (int i = 0; i < 4; ++i) diag[z * NN + row0 + ty * 4 + i] = acc[i][i];
    }
}

// ---------------- kernel 2: per-anchor triplet accumulation --------------
// dist(a,j) = g_aa + g_jj - 2*g_aj, reconstructed from the 4 partials.
// Writes per-anchor {sum, nPos} with plain stores (no global atomics).
__global__ __launch_bounds__(256) void k_triplet(const float* __restrict__ part,
                                                 const float* __restrict__ diag,
                                                 const int* __restrict__ labels,
                                                 float* __restrict__ s_part,
                                                 int* __restrict__ np_part) {
    const int a = blockIdx.x;
    const int tid = threadIdx.x;
    __shared__ float posv[NN];
    __shared__ int nPos;
    if (tid == 0) nPos = 0;
    __syncthreads();
    const int la = labels[a];
    const float g_aa = diag[0 * NN + a] + diag[1 * NN + a] + diag[2 * NN + a] + diag[3 * NN + a];
    float dval[2];
    int neg[2];
#pragma unroll
    for (int q = 0; q < 2; ++q) {
        int j = tid + q * 256;
        float g_aj = part[(size_t)0 * NN * NN + (size_t)a * NN + j] +
                     part[(size_t)1 * NN * NN + (size_t)a * NN + j] +
                     part[(size_t)2 * NN * NN + (size_t)a * NN + j] +
                     part[(size_t)3 * NN * NN + (size_t)a * NN + j];
        float g_jj = diag[0 * NN + j] + diag[1 * NN + j] + diag[2 * NN + j] + diag[3 * NN + j];
        float d = g_aa + g_jj - 2.0f * g_aj;
        dval[q] = d;
        neg[q] = 0;
        if (j != a) {
            if (labels[j] == la) {
                int p = atomicAdd(&nPos, 1);  // LDS atomic, cheap
                posv[p] = d;
            } else {
                neg[q] = 1;
            }
        }
    }
    __syncthreads();
    const int np = nPos;  // block-uniform
    float acc = 0.f;
#pragma unroll
    for (int q = 0; q < 2; ++q) {
        if (neg[q]) {
            float d = dval[q] - MARGIN_F;  // term = pos - dval + margin
            for (int p = 0; p < np; ++p) acc += fmaxf(posv[p] - d, 0.f);
        }
    }
#pragma unroll
    for (int off = 32; off > 0; off >>= 1) acc += __shfl_down(acc, off);
    __shared__ float wsum[4];
    if ((tid & 63) == 0) wsum[tid >> 6] = acc;
    __syncthreads();
    if (tid == 0) {
        s_part[a] = wsum[0] + wsum[1] + wsum[2] + wsum[3];
        np_part[a] = np;
    }
}

// ---------------- kernel 3: final reduction ------------------------------
__global__ __launch_bounds__(256) void k_reduce(const float* __restrict__ s_part,
                                                const int* __restrict__ np_part,
                                                float* __restrict__ out) {
    const int tid = threadIdx.x;
    double s = 0.0;
    long long c = 0;
    for (int i = tid; i < NN; i += 256) {
        s += (double)s_part[i];
        int np = np_part[i];
        c += (long long)np * (511 - np);
    }
#pragma unroll
    for (int off = 32; off > 0; off >>= 1) {
        s += __shfl_down(s, off);
        c += __shfl_down(c, off);
    }
    __shared__ double ws_[4];
    __shared__ long long wc_[4];
    if ((tid & 63) == 0) {
        ws_[tid >> 6] = s;
        wc_[tid >> 6] = c;
    }
    __syncthreads();
    if (tid == 0) {
        double tot = ws_[0] + ws_[1] + ws_[2] + ws_[3];
        long long cnt = wc_[0] + wc_[1] + wc_[2] + wc_[3];
        if (cnt < 1) cnt = 1;
        out[0] = (float)(tot / (double)cnt);
    }
}

extern "C" void kernel_launch(void* const* d_in, const int* in_sizes, int n_in,
                              void* d_out, int out_size, void* d_ws, size_t ws_size,
                              hipStream_t stream) {
    const float* E = (const float*)d_in[0];
    const int* labels = (const int*)d_in[1];
    float* out = (float*)d_out;

    // workspace layout (bytes)
    float* part = (float*)d_ws;                                   // 4 * 512*512*4 = 4 MiB
    float* diag = (float*)((char*)d_ws + (size_t)KSPLIT * NN * NN * 4);  // 8 KiB
    float* s_part = (float*)((char*)diag + (size_t)KSPLIT * NN * 4);     // 2 KiB
    int* np_part = (int*)((char*)s_part + (size_t)NN * 4);               // 2 KiB

    k_gram<<<dim3(NN / BN, NN / BM, KSPLIT), 256, 0, stream>>>(E, part, diag);
    k_triplet<<<NN, 256, 0, stream>>>(part, diag, labels, s_part, np_part);
    k_reduce<<<1, 256, 0, stream>>>(s_part, np_part, out);
}